// Round 8
// baseline (366.505 us; speedup 1.0000x reference)
//
#include <hip/hip_runtime.h>
#include <math.h>

// ---------------- sizes ----------------
#define NN1   10000
#define NE    160000
#define FIN   256
#define HID   500
#define K1    5000
#define NN2   5000
#define K2    2500
#define NSLAB 64
#define RORPB  79
#define RCHUNK 500

// ---------------- ws layout (float offsets) ----------------
#define CSR_OFFS   0u        // 10008 ints (offs[0..10000])
#define CSR_POS    10008u    // 10000 ints  (zeroed)
#define OFF_SC1    20008u    // 10000 f     (zeroed)
#define OFF_SC2    30008u    // 5000 f      (zeroed)
#define OFF_CTR    35008u    // 32 ints     (zeroed): 3 ro2f
#define ZERO_BASE  10008u
#define ZERO_LEN   25032u
#define CSR_EDGE   35040u    // int2 x 160000 -> 320000 floats
#define OFF_RK1X   370040u   // 10000 ints
#define OFF_PM1    385056u   // 64*500
#define OFF_PS1    417056u
#define OFF_PM2    449056u
#define OFF_PS2    481056u
#define OFF_Z      513056u   // 1000
#define OFF_T1     514056u   // 2000
#define OFF_T2     516056u   // 4000
#define OFF_INV    520056u   // 2 (+pad)
#define OFF_AGG    520064u   // bf16: max(10000*256, 5000*500) -> 1.28M floats
#define OFF_H      1800064u  // bf16 10000*500 -> 2.5M floats
#define OFF_XP1B   4300064u  // bf16 5000*500
#define OFF_XB     6175064u  // bf16 10000*256
#define OFF_W1RB   7455064u
#define OFF_W1TB   7519064u
#define OFF_W2RB   7583064u
#define OFF_W2TB   7708064u
#define OFF_CNT    7833088u  // 200000 ints (rank partial counts, pool1)
#define WS_FLOATS  8033120u

// ---------------- helpers ----------------
__device__ inline unsigned f2ord(float f) {
    unsigned u = __float_as_uint(f);
    return (u & 0x80000000u) ? ~u : (u | 0x80000000u);
}
__device__ inline unsigned long long rkey(float s, int j) {
    return ((unsigned long long)f2ord(s) << 32) | (unsigned)(0xFFFFFFFFu - (unsigned)j);
}
__device__ inline unsigned short bf16rn(float f) {
    unsigned u = __float_as_uint(f);
    u += 0x7FFFu + ((u >> 16) & 1u);
    return (unsigned short)(u >> 16);
}
__device__ inline float bf2f(unsigned short u) {
    return __uint_as_float((unsigned)u << 16);
}

typedef __attribute__((ext_vector_type(8))) short short8;
typedef __attribute__((ext_vector_type(4))) float floatx4;

// guarded 16B bf16 load
__device__ inline short8 ld8g(const unsigned short* p, int gk, int K) {
    if (gk + 7 < K) return *(const short8*)p;
    unsigned short tmp[8] = {0,0,0,0,0,0,0,0};
    for (int q = 0; q < 8; ++q) if (gk + q < K) tmp[q] = p[q];
    return *(short8*)tmp;
}

// ---------------- kernels ----------------
// NOTE (r7 lesson): no spin-wait grid sync in this harness — a single
// non-resident block deadlocks the GPU (r7 double container failure).
// Only done-counter (last-finished-block) patterns are used.

// fused prep: y<5 fp32->bf16 convert (grid-stride); y==5 p-norms;
// y==6 degree histogram (grid-stride).
__global__ __launch_bounds__(256) void k_prep(
    const float* __restrict__ x, unsigned short* __restrict__ xb,
    const float* __restrict__ w1r, unsigned short* __restrict__ w1rb,
    const float* __restrict__ w1t, unsigned short* __restrict__ w1tb,
    const float* __restrict__ w2r, unsigned short* __restrict__ w2rb,
    const float* __restrict__ w2t, unsigned short* __restrict__ w2tb,
    const float* __restrict__ p1, const float* __restrict__ p2,
    float* __restrict__ invn,
    const int* __restrict__ edst, int* __restrict__ pos) {
    __shared__ float red[256];
    int tid = threadIdx.x;
    int y = blockIdx.y;
    if (y < 5) {
        const float* s; unsigned short* d; int n4;
        switch (y) {
            case 0: s = x;   d = xb;   n4 = NN1 * FIN / 4; break;
            case 1: s = w1r; d = w1rb; n4 = HID * FIN / 4; break;
            case 2: s = w1t; d = w1tb; n4 = HID * FIN / 4; break;
            case 3: s = w2r; d = w2rb; n4 = HID * HID / 4; break;
            default: s = w2t; d = w2tb; n4 = HID * HID / 4; break;
        }
        int stride = gridDim.x * 256;
        for (int i = blockIdx.x * 256 + tid; i < n4; i += stride) {
            float4 v = *(const float4*)(s + (size_t)i * 4);
            ushort4 o;
            o.x = bf16rn(v.x); o.y = bf16rn(v.y); o.z = bf16rn(v.z); o.w = bf16rn(v.w);
            *(ushort4*)(d + (size_t)i * 4) = o;
        }
    } else if (y == 5) {
        if (blockIdx.x >= 2) return;
        const float* p = blockIdx.x ? p2 : p1;
        float s = 0.f;
        for (int i = tid; i < HID; i += 256) { float v = p[i]; s += v * v; }
        red[tid] = s; __syncthreads();
        for (int w = 128; w > 0; w >>= 1) {
            if (tid < w) red[tid] += red[tid + w];
            __syncthreads();
        }
        if (tid == 0) invn[blockIdx.x] = 1.0f / sqrtf(red[0]);
    } else {
        int stride = gridDim.x * 256;
        for (int e = blockIdx.x * 256 + tid; e < NE; e += stride)
            atomicAdd(&pos[edst[e]], 1);
    }
}

// single-block exclusive scan; writes offs[0..NN1] AND pos working copy
__global__ __launch_bounds__(1024) void k_scan(int* __restrict__ pos, int* __restrict__ offs) {
    __shared__ int tot[1024];
    int t = threadIdx.x;
    int base = t * 10;
    int loc[10]; int s = 0;
    #pragma unroll
    for (int q = 0; q < 10; ++q) {
        int v = (base + q < NN1) ? pos[base + q] : 0;
        loc[q] = s; s += v;
    }
    tot[t] = s; __syncthreads();
    for (int d = 1; d < 1024; d <<= 1) {
        int v = (t >= d) ? tot[t - d] : 0;
        __syncthreads();
        tot[t] += v;
        __syncthreads();
    }
    int excl = (t == 0) ? 0 : tot[t - 1];
    #pragma unroll
    for (int q = 0; q < 10; ++q)
        if (base + q < NN1) { int o = excl + loc[q]; offs[base + q] = o; pos[base + q] = o; }
    if (t == 1023) offs[NN1] = tot[1023];
}

// fill packed edges: one 8B store per edge
__global__ __launch_bounds__(256) void k_fill(
    const int* __restrict__ src, const int* __restrict__ dst,
    const float* __restrict__ w, int* __restrict__ pos,
    int2* __restrict__ ce) {
    int e = blockIdx.x * 256 + threadIdx.x;
    if (e >= NE) return;
    int slot = atomicAdd(&pos[dst[e]], 1);
    ce[slot] = make_int2(src[e], __float_as_int(w[e]));
}

// conv1 aggregation, 2-edge unroll with dual accumulator chains
__global__ __launch_bounds__(256) void k_gather1(
    const unsigned short* __restrict__ xb, const int* __restrict__ offs,
    const int2* __restrict__ ce, unsigned short* __restrict__ aggb) {
    int wave = (blockIdx.x * 256 + threadIdx.x) >> 6;
    int lane = threadIdx.x & 63;
    if (wave >= NN1) return;
    int b = offs[wave], e = offs[wave + 1];
    float4 a0 = make_float4(0.f, 0.f, 0.f, 0.f);
    float4 a1 = make_float4(0.f, 0.f, 0.f, 0.f);
    int p = b;
    for (; p + 1 < e; p += 2) {
        int2 e0 = ce[p], e1 = ce[p + 1];
        float w0 = __int_as_float(e0.y), w1 = __int_as_float(e1.y);
        ushort4 u0 = *(const ushort4*)(xb + (size_t)e0.x * FIN + lane * 4);
        ushort4 u1 = *(const ushort4*)(xb + (size_t)e1.x * FIN + lane * 4);
        a0.x += bf2f(u0.x) * w0; a0.y += bf2f(u0.y) * w0;
        a0.z += bf2f(u0.z) * w0; a0.w += bf2f(u0.w) * w0;
        a1.x += bf2f(u1.x) * w1; a1.y += bf2f(u1.y) * w1;
        a1.z += bf2f(u1.z) * w1; a1.w += bf2f(u1.w) * w1;
    }
    if (p < e) {
        int2 e0 = ce[p];
        float w0 = __int_as_float(e0.y);
        ushort4 u0 = *(const ushort4*)(xb + (size_t)e0.x * FIN + lane * 4);
        a0.x += bf2f(u0.x) * w0; a0.y += bf2f(u0.y) * w0;
        a0.z += bf2f(u0.z) * w0; a0.w += bf2f(u0.w) * w0;
    }
    ushort4 o;
    o.x = bf16rn(a0.x + a1.x); o.y = bf16rn(a0.y + a1.y);
    o.z = bf16rn(a0.z + a1.z); o.w = bf16rn(a0.w + a1.w);
    *(ushort4*)(aggb + (size_t)wave * FIN + lane * 4) = o;
}

// ---- bf16 MFMA GEMM: XOR-swizzled LDS, double-buffered, 2-deep prefetch ----
// C(bf16) = relu(A1@B1^T + A2@B2^T + bias); score[row] += sum(relu*pv) via atomics.
#define GBK 64
__global__ __launch_bounds__(256) void k_gemm_bf16(
    const unsigned short* __restrict__ A1, const unsigned short* __restrict__ B1,
    const unsigned short* __restrict__ A2, const unsigned short* __restrict__ B2,
    const float* __restrict__ bias, const float* __restrict__ pv,
    unsigned short* __restrict__ C, float* __restrict__ score,
    int M, int N, int Ka, int Kb, int nbyRow) {
    __shared__ unsigned short As[2][64 * 64];
    __shared__ unsigned short Bs[2][64 * 64];
    int tid = threadIdx.x;
    int b = blockIdx.x;
    int xcd = b & 7, seq = b >> 3;
    int colT = seq & 7;
    int rowT = xcd + 8 * (seq >> 3);
    if (rowT >= nbyRow) return;
    int row0 = rowT * 64, col0 = colT * 64;
    int lane = tid & 63, wid = tid >> 6;
    int waveM = wid & 1, waveN = wid >> 1;
    int quad = lane >> 4, mrow = lane & 15;
    int m7 = mrow & 7;
    floatx4 acc[2][2] = {};

    int sr = tid >> 2;
    int ca = (tid & 3) * 2;
    int s7 = sr & 7;
    int c0 = (ca ^ s7) * 8;
    int c1 = ((ca + 1) ^ s7) * 8;
    int sbase = sr * 64;

    int nka = (Ka + GBK - 1) / GBK;
    int nkb = (Kb + GBK - 1) / GBK;
    int niter = nka + nkb;

    short8 z8 = {0,0,0,0,0,0,0,0};
    short8 paA = z8, paB = z8, pbA = z8, pbB = z8;

    auto fetch = [&](int t) {
        int ph = (t >= nka);
        const unsigned short* A = ph ? A2 : A1;
        const unsigned short* B = ph ? B2 : B1;
        int K = ph ? Kb : Ka;
        int gk = (ph ? t - nka : t) * GBK + ca * 8;
        int gr = row0 + sr, gn = col0 + sr;
        paA = z8; paB = z8; pbA = z8; pbB = z8;
        if (gr < M) {
            const unsigned short* p = A + (size_t)gr * K + gk;
            paA = ld8g(p, gk, K); paB = ld8g(p + 8, gk + 8, K);
        }
        if (gn < N) {
            const unsigned short* p = B + (size_t)gn * K + gk;
            pbA = ld8g(p, gk, K); pbB = ld8g(p + 8, gk + 8, K);
        }
    };
    auto commit = [&](int buf) {
        *(short8*)&As[buf][sbase + c0] = paA;
        *(short8*)&As[buf][sbase + c1] = paB;
        *(short8*)&Bs[buf][sbase + c0] = pbA;
        *(short8*)&Bs[buf][sbase + c1] = pbB;
    };

    fetch(0);
    commit(0);
    if (niter > 1) fetch(1);
    __syncthreads();

    for (int it = 0; it < niter; ++it) {
        int cur = it & 1;
        if (it + 1 < niter) commit(cur ^ 1);
        if (it + 2 < niter) fetch(it + 2);
        #pragma unroll
        for (int half = 0; half < 2; ++half) {
            int qc = half * 4 + quad;
            int qoff = (qc ^ m7) * 8;
            short8 bfr[2];
            #pragma unroll
            for (int nt = 0; nt < 2; ++nt)
                bfr[nt] = *(short8*)&Bs[cur][(waveN * 32 + nt * 16 + mrow) * 64 + qoff];
            #pragma unroll
            for (int mt = 0; mt < 2; ++mt) {
                short8 afr = *(short8*)&As[cur][(waveM * 32 + mt * 16 + mrow) * 64 + qoff];
                #pragma unroll
                for (int nt = 0; nt < 2; ++nt)
                    acc[mt][nt] = __builtin_amdgcn_mfma_f32_16x16x32_bf16(
                        afr, bfr[nt], acc[mt][nt], 0, 0, 0);
            }
        }
        __syncthreads();
    }
    // epilogue: bias + relu -> bf16 C; score partials via atomics
    float ps[2][4] = {};
    #pragma unroll
    for (int nt = 0; nt < 2; ++nt) {
        int col = col0 + waveN * 32 + nt * 16 + mrow;
        if (col >= N) continue;
        float bv = bias[col];
        float pc = pv[col];
        #pragma unroll
        for (int mt = 0; mt < 2; ++mt) {
            int rbase = row0 + waveM * 32 + mt * 16 + quad * 4;
            #pragma unroll
            for (int r = 0; r < 4; ++r) {
                float v = fmaxf(acc[mt][nt][r] + bv, 0.f);
                int row = rbase + r;
                if (row < M) C[(size_t)row * N + col] = bf16rn(v);
                ps[mt][r] += v * pc;
            }
        }
    }
    #pragma unroll
    for (int mt = 0; mt < 2; ++mt)
        #pragma unroll
        for (int r = 0; r < 4; ++r) {
            float v = ps[mt][r];
            v += __shfl_xor(v, 1, 64); v += __shfl_xor(v, 2, 64);
            v += __shfl_xor(v, 4, 64); v += __shfl_xor(v, 8, 64);
            if (mrow == 0) {
                int row = row0 + waveM * 32 + mt * 16 + quad * 4 + r;
                if (row < M) atomicAdd(&score[row], v);
            }
        }
}

// parallel count-based rank partials (pool1): cntp[chunkY][i] = |{j in chunk : key_j > key_i}|
__global__ __launch_bounds__(256) void k_rank_partial(
    const float* __restrict__ score, int* __restrict__ cntp, int Nn) {
    __shared__ unsigned long long kj[RCHUNK];
    int j0 = blockIdx.y * RCHUNK;
    int jn = min(Nn - j0, RCHUNK);
    for (int t = threadIdx.x; t < jn; t += 256)
        kj[t] = rkey(score[j0 + t], j0 + t);
    __syncthreads();
    int i = blockIdx.x * 256 + threadIdx.x;
    if (i >= Nn) return;
    unsigned long long ki = rkey(score[i], i);
    int c = 0;
    #pragma unroll 4
    for (int q = 0; q < jn; ++q)
        c += (kj[q] > ki) ? 1 : 0;
    cntp[(size_t)blockIdx.y * Nn + i] = c;
}

// pool1: wave-per-row rank finalize + gather
__global__ __launch_bounds__(256) void k_gather_pool(
    const unsigned short* __restrict__ Hb, const float* __restrict__ score,
    const float* __restrict__ invn,
    const int* __restrict__ cntp, int Nn, int nchunk, int kk,
    int* __restrict__ rank_out, unsigned short* __restrict__ Xb) {
    int wave = (blockIdx.x * 256 + threadIdx.x) >> 6;
    int lane = threadIdx.x & 63;
    int nw = gridDim.x * 4;
    for (int i = wave; i < Nn; i += nw) {
        int c = (lane < nchunk) ? cntp[(size_t)lane * Nn + i] : 0;
        for (int off = 32; off > 0; off >>= 1) c += __shfl_down(c, off, 64);
        c = __shfl(c, 0, 64);
        int r = (c < kk) ? c : -1;
        if (lane == 0) rank_out[i] = r;
        if (r < 0) continue;
        float sc = tanhf(score[i] * invn[0]);
        const ushort4* src = (const ushort4*)(Hb + (size_t)i * HID);
        ushort4* dst = (ushort4*)(Xb + (size_t)r * HID);
        ushort4 u = src[lane];
        ushort4 o;
        o.x = bf16rn(bf2f(u.x) * sc); o.y = bf16rn(bf2f(u.y) * sc);
        o.z = bf16rn(bf2f(u.z) * sc); o.w = bf16rn(bf2f(u.w) * sc);
        dst[lane] = o;
        if (lane < HID / 4 - 64) {
            ushort4 u2 = src[lane + 64];
            ushort4 o2;
            o2.x = bf16rn(bf2f(u2.x) * sc); o2.y = bf16rn(bf2f(u2.y) * sc);
            o2.z = bf16rn(bf2f(u2.z) * sc); o2.w = bf16rn(bf2f(u2.w) * sc);
            dst[lane + 64] = o2;
        }
    }
}

// shared readout slab body: per-slab column max+sum over bf16 rows
__device__ void readout_slab(const unsigned short* __restrict__ X, int rows, int rpb,
                             int slabY, int colHalf,
                             float* __restrict__ pmax, float* __restrict__ psum) {
    __shared__ float4 lmx[4][64];
    __shared__ float4 lsm[4][64];
    int lane = threadIdx.x & 63;
    int rgrp = threadIdx.x >> 6;
    int c4 = colHalf * 64 + lane;
    int r0 = slabY * rpb;
    int r1 = min(rows, r0 + rpb);
    float4 mx = make_float4(-INFINITY, -INFINITY, -INFINITY, -INFINITY);
    float4 sm = make_float4(0.f, 0.f, 0.f, 0.f);
    if (c4 < HID / 4) {
        for (int r = r0 + rgrp; r < r1; r += 4) {
            ushort4 u = *(const ushort4*)(X + (size_t)r * HID + c4 * 4);
            float vx = bf2f(u.x), vy = bf2f(u.y), vz = bf2f(u.z), vw = bf2f(u.w);
            mx.x = fmaxf(mx.x, vx); mx.y = fmaxf(mx.y, vy);
            mx.z = fmaxf(mx.z, vz); mx.w = fmaxf(mx.w, vw);
            sm.x += vx; sm.y += vy; sm.z += vz; sm.w += vw;
        }
    }
    lmx[rgrp][lane] = mx; lsm[rgrp][lane] = sm;
    __syncthreads();
    if (rgrp == 0 && c4 < HID / 4) {
        #pragma unroll
        for (int g = 1; g < 4; ++g) {
            float4 m2 = lmx[g][lane], s2 = lsm[g][lane];
            mx.x = fmaxf(mx.x, m2.x); mx.y = fmaxf(mx.y, m2.y);
            mx.z = fmaxf(mx.z, m2.z); mx.w = fmaxf(mx.w, m2.w);
            sm.x += s2.x; sm.y += s2.y; sm.z += s2.z; sm.w += s2.w;
        }
        *(float4*)(pmax + (size_t)slabY * HID + c4 * 4) = mx;
        *(float4*)(psum + (size_t)slabY * HID + c4 * 4) = sm;
    }
}

// role-split: blocks <2500 do conv2 aggregation; the rest do pool1 readout
__global__ __launch_bounds__(256) void k_g2r1(
    const unsigned short* __restrict__ xp1, const int* __restrict__ offs,
    const int2* __restrict__ ce, const int* __restrict__ rank,
    unsigned short* __restrict__ aggb,
    float* __restrict__ pm1, float* __restrict__ ps1) {
    if (blockIdx.x < 2500) {
        int wave = (blockIdx.x * 256 + threadIdx.x) >> 6;
        int lane = threadIdx.x & 63;
        int rd = rank[wave];
        if (rd < 0) return;
        int b = offs[wave], e = offs[wave + 1];
        int c1 = 256 + lane * 4;
        float a0 = 0.f, a1 = 0.f, a2 = 0.f, a3 = 0.f;
        float b0 = 0.f, b1v = 0.f, b2 = 0.f, b3 = 0.f;
        int2 nxt = (b < e) ? ce[b] : make_int2(0, 0);
        for (int p = b; p < e; ++p) {
            int2 cur = nxt;
            if (p + 1 < e) nxt = ce[p + 1];
            int rs = rank[cur.x];
            if (rs < 0) continue;
            float we = __int_as_float(cur.y);
            const unsigned short* row = xp1 + (size_t)rs * HID;
            ushort4 u = *(const ushort4*)(row + lane * 4);
            a0 += bf2f(u.x) * we; a1 += bf2f(u.y) * we;
            a2 += bf2f(u.z) * we; a3 += bf2f(u.w) * we;
            if (c1 < HID) {
                ushort4 u2 = *(const ushort4*)(row + c1);
                b0 += bf2f(u2.x) * we; b1v += bf2f(u2.y) * we;
                b2 += bf2f(u2.z) * we; b3 += bf2f(u2.w) * we;
            }
        }
        unsigned short* o = aggb + (size_t)rd * HID;
        ushort4 o1; o1.x = bf16rn(a0); o1.y = bf16rn(a1); o1.z = bf16rn(a2); o1.w = bf16rn(a3);
        *(ushort4*)(o + lane * 4) = o1;
        if (c1 < HID) {
            ushort4 o2; o2.x = bf16rn(b0); o2.y = bf16rn(b1v); o2.z = bf16rn(b2); o2.w = bf16rn(b3);
            *(ushort4*)(o + c1) = o2;
        }
    } else {
        int b = blockIdx.x - 2500;
        readout_slab(xp1, K1, RORPB, b >> 1, b & 1, pm1, ps1);
    }
}

// fused pool2: single-pass rank (chunked LDS keys, half-split per row) +
// masked readout directly from hb + done-counter combine tail -> z[1000].
__global__ __launch_bounds__(256) void k_ro2f(
    const unsigned short* __restrict__ hb, const float* __restrict__ score,
    const float* __restrict__ invn,
    float* __restrict__ pm2, float* __restrict__ ps2,
    const float* __restrict__ pm1, const float* __restrict__ ps1,
    float* __restrict__ z, int* __restrict__ donectr) {
    __shared__ unsigned long long kj[2500];
    __shared__ int rk_s[RORPB];
    __shared__ float sc_s[RORPB];
    __shared__ float4 lmx[4][64];
    __shared__ float4 lsm[4][64];
    __shared__ int flag;
    int tid = threadIdx.x;
    int slabY = blockIdx.x >> 1, colHalf = blockIdx.x & 1;
    int r0 = slabY * RORPB;
    // rank phase: rows r0..r0+78 vs all 5000 keys (exact count-of-greater)
    int rl = tid >> 1, half = tid & 1;
    int row = r0 + rl;
    bool act = (rl < RORPB) && (row < NN2);
    unsigned long long ki = act ? rkey(score[row], row) : 0ULL;
    int cnt = 0;
    for (int c = 0; c < 2; ++c) {
        int j0 = c * 2500;
        __syncthreads();
        for (int j = tid; j < 2500; j += 256)
            kj[j] = rkey(score[j0 + j], j0 + j);
        __syncthreads();
        if (act) {
            int bb = half * 1250;
            #pragma unroll 4
            for (int q = 0; q < 1250; ++q)
                cnt += (kj[bb + q] > ki) ? 1 : 0;
        }
    }
    int tot = cnt + __shfl_xor(cnt, 1, 64);
    if (act && half == 0) {
        rk_s[rl] = (tot < K2) ? 1 : 0;
        sc_s[rl] = tanhf(score[row] * invn[0]);
    }
    __syncthreads();
    // slab max/sum phase (mask+scale from LDS)
    int lane = tid & 63;
    int rgrp = tid >> 6;
    int c4 = colHalf * 64 + lane;
    int r1 = min(NN2, r0 + RORPB);
    float4 mx = make_float4(-INFINITY, -INFINITY, -INFINITY, -INFINITY);
    float4 sm = make_float4(0.f, 0.f, 0.f, 0.f);
    if (c4 < HID / 4) {
        for (int r = r0 + rgrp; r < r1; r += 4) {
            if (!rk_s[r - r0]) continue;
            float sc = sc_s[r - r0];
            ushort4 u = *(const ushort4*)(hb + (size_t)r * HID + c4 * 4);
            float vx = bf2f(u.x) * sc, vy = bf2f(u.y) * sc;
            float vz = bf2f(u.z) * sc, vw = bf2f(u.w) * sc;
            mx.x = fmaxf(mx.x, vx); mx.y = fmaxf(mx.y, vy);
            mx.z = fmaxf(mx.z, vz); mx.w = fmaxf(mx.w, vw);
            sm.x += vx; sm.y += vy; sm.z += vz; sm.w += vw;
        }
    }
    lmx[rgrp][lane] = mx; lsm[rgrp][lane] = sm;
    __syncthreads();
    if (rgrp == 0 && c4 < HID / 4) {
        #pragma unroll
        for (int g = 1; g < 4; ++g) {
            float4 m2 = lmx[g][lane], s2 = lsm[g][lane];
            mx.x = fmaxf(mx.x, m2.x); mx.y = fmaxf(mx.y, m2.y);
            mx.z = fmaxf(mx.z, m2.z); mx.w = fmaxf(mx.w, m2.w);
            sm.x += s2.x; sm.y += s2.y; sm.z += s2.z; sm.w += s2.w;
        }
        *(float4*)(pm2 + (size_t)slabY * HID + c4 * 4) = mx;
        *(float4*)(ps2 + (size_t)slabY * HID + c4 * 4) = sm;
    }
    // done-counter: last block combines both pools -> z
    if (tid == 0) {
        __threadfence();
        flag = (atomicAdd(donectr, 1) == (int)gridDim.x - 1) ? 1 : 0;
    }
    __syncthreads();
    if (!flag) return;
    __threadfence();
    for (int j = tid; j < HID; j += 256) {
        float m1 = -INFINITY, s1 = 0.f, m2v = -INFINITY, s2v = 0.f;
        for (int s = 0; s < NSLAB; ++s) {
            m1 = fmaxf(m1, pm1[(size_t)s * HID + j]); s1 += ps1[(size_t)s * HID + j];
            m2v = fmaxf(m2v, pm2[(size_t)s * HID + j]); s2v += ps2[(size_t)s * HID + j];
        }
        z[j] = m1 + m2v;
        z[HID + j] = s1 * (1.0f / (float)K1) + s2v * (1.0f / (float)K2);
    }
}

__global__ __launch_bounds__(256) void k_mv(
    const float* __restrict__ v, const float* __restrict__ W,
    const float* __restrict__ bias, float* __restrict__ y,
    int rowsN, int K, int act) {
    int wave = (blockIdx.x * 256 + threadIdx.x) >> 6;
    int lane = threadIdx.x & 63;
    if (wave >= rowsN) return;
    const float* wr = W + (size_t)wave * K;
    float s = 0.f;
    for (int c = lane * 4; c < K; c += 256) {
        float4 a = *(const float4*)(wr + c);
        float4 xv = *(const float4*)(v + c);
        s += a.x * xv.x + a.y * xv.y + a.z * xv.z + a.w * xv.w;
    }
    for (int off = 32; off > 0; off >>= 1) s += __shfl_down(s, off, 64);
    if (lane == 0) {
        float r = s + bias[wave];
        y[wave] = (act == 0) ? fmaxf(r, 0.f) : 1.f / (1.f + expf(-r));
    }
}

// ---------------- launch ----------------
extern "C" void kernel_launch(void* const* d_in, const int* in_sizes, int n_in,
                              void* d_out, int out_size, void* d_ws, size_t ws_size,
                              hipStream_t stream) {
    const float* x      = (const float*)d_in[0];
    const int*   esrc   = (const int*)d_in[1];
    const int*   edst   = (const int*)d_in[2];
    const float* ew     = (const float*)d_in[3];
    const float* W1_rel = (const float*)d_in[4];
    const float* b1     = (const float*)d_in[5];
    const float* W1_root= (const float*)d_in[6];
    const float* p1     = (const float*)d_in[7];
    const float* W2_rel = (const float*)d_in[8];
    const float* b2     = (const float*)d_in[9];
    const float* W2_root= (const float*)d_in[10];
    const float* p2     = (const float*)d_in[11];
    const float* l1W    = (const float*)d_in[12];
    const float* l1b    = (const float*)d_in[13];
    const float* l2W    = (const float*)d_in[14];
    const float* l2b    = (const float*)d_in[15];
    const float* l3W    = (const float*)d_in[16];
    const float* l3b    = (const float*)d_in[17];
    float* out = (float*)d_out;
    float* ws  = (float*)d_ws;

    if (ws_size < (size_t)WS_FLOATS * sizeof(float)) return;

    int*            offs   = (int*)(ws + CSR_OFFS);
    int*            pos    = (int*)(ws + CSR_POS);
    float*          score1 = ws + OFF_SC1;
    float*          score2 = ws + OFF_SC2;
    int*            ctr    = (int*)(ws + OFF_CTR);
    int2*           ce     = (int2*)(ws + CSR_EDGE);
    int*            rk1    = (int*)(ws + OFF_RK1X);
    float*          pm1    = ws + OFF_PM1;
    float*          ps1    = ws + OFF_PS1;
    float*          pm2    = ws + OFF_PM2;
    float*          ps2    = ws + OFF_PS2;
    float*          zbuf   = ws + OFF_Z;
    float*          t1     = ws + OFF_T1;
    float*          t2     = ws + OFF_T2;
    float*          invn   = ws + OFF_INV;
    int*            cntp   = (int*)(ws + OFF_CNT);
    unsigned short* aggb   = (unsigned short*)(ws + OFF_AGG);
    unsigned short* hb     = (unsigned short*)(ws + OFF_H);
    unsigned short* xp1b   = (unsigned short*)(ws + OFF_XP1B);
    unsigned short* xb     = (unsigned short*)(ws + OFF_XB);
    unsigned short* w1rb   = (unsigned short*)(ws + OFF_W1RB);
    unsigned short* w1tb   = (unsigned short*)(ws + OFF_W1TB);
    unsigned short* w2rb   = (unsigned short*)(ws + OFF_W2RB);
    unsigned short* w2tb   = (unsigned short*)(ws + OFF_W2TB);

    // zero: pos, score1, score2, counters (one contiguous range)
    hipMemsetAsync(ws + ZERO_BASE, 0, (size_t)ZERO_LEN * sizeof(float), stream);

    k_prep<<<dim3(640, 7), 256, 0, stream>>>(
        x, xb, W1_rel, w1rb, W1_root, w1tb, W2_rel, w2rb, W2_root, w2tb,
        p1, p2, invn, edst, pos);
    k_scan<<<1, 1024, 0, stream>>>(pos, offs);
    k_fill<<<(NE + 255) / 256, 256, 0, stream>>>(esrc, edst, ew, pos, ce);

    // conv1 (+fused score atomics)
    k_gather1<<<(NN1 * 64) / 256, 256, 0, stream>>>(xb, offs, ce, aggb);
    {
        int nby = (NN1 + 63) / 64;                 // 157
        int nblk = 64 * ((nby + 7) / 8);           // 1280
        k_gemm_bf16<<<nblk, 256, 0, stream>>>(
            aggb, w1rb, xb, w1tb, b1, p1, hb, score1, NN1, HID, FIN, FIN, nby);
    }

    // pool1: parallel count-rank + wave-per-row gather
    k_rank_partial<<<dim3((NN1 + 255) / 256, NN1 / RCHUNK), 256, 0, stream>>>(
        score1, cntp, NN1);
    k_gather_pool<<<1250, 256, 0, stream>>>(
        hb, score1, invn + 0, cntp, NN1, NN1 / RCHUNK, K1, rk1, xp1b);

    // conv2 aggregation || pool1 readout, then conv2 GEMM
    k_g2r1<<<2500 + 2 * NSLAB, 256, 0, stream>>>(xp1b, offs, ce, rk1, aggb, pm1, ps1);
    {
        int nby = (NN2 + 63) / 64;                 // 79
        int nblk = 64 * ((nby + 7) / 8);           // 640
        k_gemm_bf16<<<nblk, 256, 0, stream>>>(
            aggb, w2rb, xp1b, w2tb, b2, p2, hb, score2, NN2, HID, HID, HID, nby);
    }

    // fused pool2 rank + readout2 + combine -> z
    k_ro2f<<<2 * NSLAB, 256, 0, stream>>>(
        hb, score2, invn + 1, pm2, ps2, pm1, ps1, zbuf, ctr + 3);

    // MLP
    k_mv<<<(2000 * 64) / 256, 256, 0, stream>>>(zbuf, l1W, l1b, t1, 2000, 1000, 0);
    k_mv<<<(4000 * 64) / 256, 256, 0, stream>>>(t1, l2W, l2b, t2, 4000, 2000, 0);
    k_mv<<<(100 * 64) / 256, 256, 0, stream>>>(t2, l3W, l3b, out, 100, 4000, 1);
}

// Round 9
// 323.570 us; speedup vs baseline: 1.1327x; 1.1327x over previous
//
#include <hip/hip_runtime.h>
#include <math.h>

// ---------------- sizes ----------------
#define NN1   10000
#define NE    160000
#define FIN   256
#define HID   500
#define K1    5000
#define NN2   5000
#define K2    2500
#define NSLAB 64
#define RORPB  79
#define PRCH  2500

// ---------------- ws layout (float offsets) ----------------
#define CSR_OFFS   0u        // 10008 ints (offs[0..10000])
#define CSR_POS    10008u    // 10000 ints  (zeroed)
#define OFF_SC1    20008u    // 10000 f     (zeroed)
#define OFF_SC2    30008u    // 5000 f      (zeroed)
#define OFF_CTR    35008u    // 32 ints     (zeroed): 3 readout2
#define ZERO_BASE  10008u
#define ZERO_LEN   25032u
#define CSR_EDGE   35040u    // int2 x 160000 -> 320000 floats
#define OFF_SCALE2 365040u   // 5000
#define OFF_RK1    370040u   // 10000 ints
#define OFF_RK2    380040u   // 5000 ints
#define OFF_PM1    385056u   // 64*500
#define OFF_PS1    417056u
#define OFF_PM2    449056u
#define OFF_PS2    481056u
#define OFF_Z      513056u   // 1000
#define OFF_T1     514056u   // 2000
#define OFF_T2     516056u   // 4000
#define OFF_INV    520056u   // 2 (+pad)
#define OFF_AGG    520064u   // bf16: max(10000*256, 5000*500) -> 1.28M floats
#define OFF_H      1800064u  // bf16 10000*500 -> 2.5M floats
#define OFF_XP1B   4300064u  // bf16 5000*500
#define OFF_XB     6175064u  // bf16 10000*256
#define OFF_W1RB   7455064u
#define OFF_W1TB   7519064u
#define OFF_W2RB   7583064u
#define OFF_W2TB   7708064u
#define WS_FLOATS  8033120u

// ---------------- helpers ----------------
__device__ inline unsigned f2ord(float f) {
    unsigned u = __float_as_uint(f);
    return (u & 0x80000000u) ? ~u : (u | 0x80000000u);
}
__device__ inline unsigned long long rkey(float s, int j) {
    return ((unsigned long long)f2ord(s) << 32) | (unsigned)(0xFFFFFFFFu - (unsigned)j);
}
__device__ inline unsigned short bf16rn(float f) {
    unsigned u = __float_as_uint(f);
    u += 0x7FFFu + ((u >> 16) & 1u);
    return (unsigned short)(u >> 16);
}
__device__ inline float bf2f(unsigned short u) {
    return __uint_as_float((unsigned)u << 16);
}

typedef __attribute__((ext_vector_type(8))) short short8;
typedef __attribute__((ext_vector_type(4))) float floatx4;

// guarded 16B bf16 load
__device__ inline short8 ld8g(const unsigned short* p, int gk, int K) {
    if (gk + 7 < K) return *(const short8*)p;
    unsigned short tmp[8] = {0,0,0,0,0,0,0,0};
    for (int q = 0; q < 8; ++q) if (gk + q < K) tmp[q] = p[q];
    return *(short8*)tmp;
}

// ---------------- kernels ----------------
// r7/r8 lessons: no spin-wait sync (deadlock risk); fused phases must keep the
// SAME parallelism as the kernels they replace (r8's 128-block rank = 96us).

// fused prep: y<5 fp32->bf16 convert (grid-stride); y==5 p-norms;
// y==6 degree histogram (grid-stride).
__global__ __launch_bounds__(256) void k_prep(
    const float* __restrict__ x, unsigned short* __restrict__ xb,
    const float* __restrict__ w1r, unsigned short* __restrict__ w1rb,
    const float* __restrict__ w1t, unsigned short* __restrict__ w1tb,
    const float* __restrict__ w2r, unsigned short* __restrict__ w2rb,
    const float* __restrict__ w2t, unsigned short* __restrict__ w2tb,
    const float* __restrict__ p1, const float* __restrict__ p2,
    float* __restrict__ invn,
    const int* __restrict__ edst, int* __restrict__ pos) {
    __shared__ float red[256];
    int tid = threadIdx.x;
    int y = blockIdx.y;
    if (y < 5) {
        const float* s; unsigned short* d; int n4;
        switch (y) {
            case 0: s = x;   d = xb;   n4 = NN1 * FIN / 4; break;
            case 1: s = w1r; d = w1rb; n4 = HID * FIN / 4; break;
            case 2: s = w1t; d = w1tb; n4 = HID * FIN / 4; break;
            case 3: s = w2r; d = w2rb; n4 = HID * HID / 4; break;
            default: s = w2t; d = w2tb; n4 = HID * HID / 4; break;
        }
        int stride = gridDim.x * 256;
        for (int i = blockIdx.x * 256 + tid; i < n4; i += stride) {
            float4 v = *(const float4*)(s + (size_t)i * 4);
            ushort4 o;
            o.x = bf16rn(v.x); o.y = bf16rn(v.y); o.z = bf16rn(v.z); o.w = bf16rn(v.w);
            *(ushort4*)(d + (size_t)i * 4) = o;
        }
    } else if (y == 5) {
        if (blockIdx.x >= 2) return;
        const float* p = blockIdx.x ? p2 : p1;
        float s = 0.f;
        for (int i = tid; i < HID; i += 256) { float v = p[i]; s += v * v; }
        red[tid] = s; __syncthreads();
        for (int w = 128; w > 0; w >>= 1) {
            if (tid < w) red[tid] += red[tid + w];
            __syncthreads();
        }
        if (tid == 0) invn[blockIdx.x] = 1.0f / sqrtf(red[0]);
    } else {
        int stride = gridDim.x * 256;
        for (int e = blockIdx.x * 256 + tid; e < NE; e += stride)
            atomicAdd(&pos[edst[e]], 1);
    }
}

// single-block exclusive scan; writes offs[0..NN1] AND pos working copy
__global__ __launch_bounds__(1024) void k_scan(int* __restrict__ pos, int* __restrict__ offs) {
    __shared__ int tot[1024];
    int t = threadIdx.x;
    int base = t * 10;
    int loc[10]; int s = 0;
    #pragma unroll
    for (int q = 0; q < 10; ++q) {
        int v = (base + q < NN1) ? pos[base + q] : 0;
        loc[q] = s; s += v;
    }
    tot[t] = s; __syncthreads();
    for (int d = 1; d < 1024; d <<= 1) {
        int v = (t >= d) ? tot[t - d] : 0;
        __syncthreads();
        tot[t] += v;
        __syncthreads();
    }
    int excl = (t == 0) ? 0 : tot[t - 1];
    #pragma unroll
    for (int q = 0; q < 10; ++q)
        if (base + q < NN1) { int o = excl + loc[q]; offs[base + q] = o; pos[base + q] = o; }
    if (t == 1023) offs[NN1] = tot[1023];
}

// fill packed edges: one 8B store per edge
__global__ __launch_bounds__(256) void k_fill(
    const int* __restrict__ src, const int* __restrict__ dst,
    const float* __restrict__ w, int* __restrict__ pos,
    int2* __restrict__ ce) {
    int e = blockIdx.x * 256 + threadIdx.x;
    if (e >= NE) return;
    int slot = atomicAdd(&pos[dst[e]], 1);
    ce[slot] = make_int2(src[e], __float_as_int(w[e]));
}

// conv1 aggregation, 2-edge unroll with dual accumulator chains
__global__ __launch_bounds__(256) void k_gather1(
    const unsigned short* __restrict__ xb, const int* __restrict__ offs,
    const int2* __restrict__ ce, unsigned short* __restrict__ aggb) {
    int wave = (blockIdx.x * 256 + threadIdx.x) >> 6;
    int lane = threadIdx.x & 63;
    if (wave >= NN1) return;
    int b = offs[wave], e = offs[wave + 1];
    float4 a0 = make_float4(0.f, 0.f, 0.f, 0.f);
    float4 a1 = make_float4(0.f, 0.f, 0.f, 0.f);
    int p = b;
    for (; p + 1 < e; p += 2) {
        int2 e0 = ce[p], e1 = ce[p + 1];
        float w0 = __int_as_float(e0.y), w1 = __int_as_float(e1.y);
        ushort4 u0 = *(const ushort4*)(xb + (size_t)e0.x * FIN + lane * 4);
        ushort4 u1 = *(const ushort4*)(xb + (size_t)e1.x * FIN + lane * 4);
        a0.x += bf2f(u0.x) * w0; a0.y += bf2f(u0.y) * w0;
        a0.z += bf2f(u0.z) * w0; a0.w += bf2f(u0.w) * w0;
        a1.x += bf2f(u1.x) * w1; a1.y += bf2f(u1.y) * w1;
        a1.z += bf2f(u1.z) * w1; a1.w += bf2f(u1.w) * w1;
    }
    if (p < e) {
        int2 e0 = ce[p];
        float w0 = __int_as_float(e0.y);
        ushort4 u0 = *(const ushort4*)(xb + (size_t)e0.x * FIN + lane * 4);
        a0.x += bf2f(u0.x) * w0; a0.y += bf2f(u0.y) * w0;
        a0.z += bf2f(u0.z) * w0; a0.w += bf2f(u0.w) * w0;
    }
    ushort4 o;
    o.x = bf16rn(a0.x + a1.x); o.y = bf16rn(a0.y + a1.y);
    o.z = bf16rn(a0.z + a1.z); o.w = bf16rn(a0.w + a1.w);
    *(ushort4*)(aggb + (size_t)wave * FIN + lane * 4) = o;
}

// ---- bf16 MFMA GEMM: XOR-swizzled LDS, double-buffered, 2-deep prefetch ----
// C(bf16) = relu(A1@B1^T + A2@B2^T + bias); score[row] += sum(relu*pv) via atomics.
#define GBK 64
__global__ __launch_bounds__(256) void k_gemm_bf16(
    const unsigned short* __restrict__ A1, const unsigned short* __restrict__ B1,
    const unsigned short* __restrict__ A2, const unsigned short* __restrict__ B2,
    const float* __restrict__ bias, const float* __restrict__ pv,
    unsigned short* __restrict__ C, float* __restrict__ score,
    int M, int N, int Ka, int Kb, int nbyRow) {
    __shared__ unsigned short As[2][64 * 64];
    __shared__ unsigned short Bs[2][64 * 64];
    int tid = threadIdx.x;
    int b = blockIdx.x;
    int xcd = b & 7, seq = b >> 3;
    int colT = seq & 7;
    int rowT = xcd + 8 * (seq >> 3);
    if (rowT >= nbyRow) return;
    int row0 = rowT * 64, col0 = colT * 64;
    int lane = tid & 63, wid = tid >> 6;
    int waveM = wid & 1, waveN = wid >> 1;
    int quad = lane >> 4, mrow = lane & 15;
    int m7 = mrow & 7;
    floatx4 acc[2][2] = {};

    int sr = tid >> 2;
    int ca = (tid & 3) * 2;
    int s7 = sr & 7;
    int c0 = (ca ^ s7) * 8;
    int c1 = ((ca + 1) ^ s7) * 8;
    int sbase = sr * 64;

    int nka = (Ka + GBK - 1) / GBK;
    int nkb = (Kb + GBK - 1) / GBK;
    int niter = nka + nkb;

    short8 z8 = {0,0,0,0,0,0,0,0};
    short8 paA = z8, paB = z8, pbA = z8, pbB = z8;

    auto fetch = [&](int t) {
        int ph = (t >= nka);
        const unsigned short* A = ph ? A2 : A1;
        const unsigned short* B = ph ? B2 : B1;
        int K = ph ? Kb : Ka;
        int gk = (ph ? t - nka : t) * GBK + ca * 8;
        int gr = row0 + sr, gn = col0 + sr;
        paA = z8; paB = z8; pbA = z8; pbB = z8;
        if (gr < M) {
            const unsigned short* p = A + (size_t)gr * K + gk;
            paA = ld8g(p, gk, K); paB = ld8g(p + 8, gk + 8, K);
        }
        if (gn < N) {
            const unsigned short* p = B + (size_t)gn * K + gk;
            pbA = ld8g(p, gk, K); pbB = ld8g(p + 8, gk + 8, K);
        }
    };
    auto commit = [&](int buf) {
        *(short8*)&As[buf][sbase + c0] = paA;
        *(short8*)&As[buf][sbase + c1] = paB;
        *(short8*)&Bs[buf][sbase + c0] = pbA;
        *(short8*)&Bs[buf][sbase + c1] = pbB;
    };

    fetch(0);
    commit(0);
    if (niter > 1) fetch(1);
    __syncthreads();

    for (int it = 0; it < niter; ++it) {
        int cur = it & 1;
        if (it + 1 < niter) commit(cur ^ 1);
        if (it + 2 < niter) fetch(it + 2);
        #pragma unroll
        for (int half = 0; half < 2; ++half) {
            int qc = half * 4 + quad;
            int qoff = (qc ^ m7) * 8;
            short8 bfr[2];
            #pragma unroll
            for (int nt = 0; nt < 2; ++nt)
                bfr[nt] = *(short8*)&Bs[cur][(waveN * 32 + nt * 16 + mrow) * 64 + qoff];
            #pragma unroll
            for (int mt = 0; mt < 2; ++mt) {
                short8 afr = *(short8*)&As[cur][(waveM * 32 + mt * 16 + mrow) * 64 + qoff];
                #pragma unroll
                for (int nt = 0; nt < 2; ++nt)
                    acc[mt][nt] = __builtin_amdgcn_mfma_f32_16x16x32_bf16(
                        afr, bfr[nt], acc[mt][nt], 0, 0, 0);
            }
        }
        __syncthreads();
    }
    // epilogue: bias + relu -> bf16 C; score partials via atomics
    float ps[2][4] = {};
    #pragma unroll
    for (int nt = 0; nt < 2; ++nt) {
        int col = col0 + waveN * 32 + nt * 16 + mrow;
        if (col >= N) continue;
        float bv = bias[col];
        float pc = pv[col];
        #pragma unroll
        for (int mt = 0; mt < 2; ++mt) {
            int rbase = row0 + waveM * 32 + mt * 16 + quad * 4;
            #pragma unroll
            for (int r = 0; r < 4; ++r) {
                float v = fmaxf(acc[mt][nt][r] + bv, 0.f);
                int row = rbase + r;
                if (row < M) C[(size_t)row * N + col] = bf16rn(v);
                ps[mt][r] += v * pc;
            }
        }
    }
    #pragma unroll
    for (int mt = 0; mt < 2; ++mt)
        #pragma unroll
        for (int r = 0; r < 4; ++r) {
            float v = ps[mt][r];
            v += __shfl_xor(v, 1, 64); v += __shfl_xor(v, 2, 64);
            v += __shfl_xor(v, 4, 64); v += __shfl_xor(v, 8, 64);
            if (mrow == 0) {
                int row = row0 + waveM * 32 + mt * 16 + quad * 4 + r;
                if (row < M) atomicAdd(&score[row], v);
            }
        }
}

// fused rank+gather, FULL parallelism (r8 lesson): wave-per-4-rows, keys staged
// chunk-wise in LDS, per-lane strided count with 4 independent chains.
// Replaces rank_partial (+cntp round-trip) + finalize/gather = 1 launch/pool.
// If Xb: scale+compact kept rows (pool1). If scale_out: write tanh scale (pool2).
__global__ __launch_bounds__(256) void k_poolrank(
    const unsigned short* __restrict__ Hb, const float* __restrict__ score,
    const float* __restrict__ invn, int Nn, int kk,
    int* __restrict__ rank_out, float* __restrict__ scale_out,
    unsigned short* __restrict__ Xb) {
    __shared__ unsigned long long kj[PRCH];
    int tid = threadIdx.x;
    int lane = tid & 63;
    int w = blockIdx.x * 4 + (tid >> 6);
    int i0 = w * 4;
    unsigned long long ki[4];
    #pragma unroll
    for (int r = 0; r < 4; ++r) {
        int i = i0 + r;
        ki[r] = (i < Nn) ? rkey(score[i], i) : 0xFFFFFFFFFFFFFFFFull;
    }
    int cnt[4] = {0, 0, 0, 0};
    int nch = (Nn + PRCH - 1) / PRCH;
    for (int c = 0; c < nch; ++c) {
        int j0 = c * PRCH;
        int jn = min(Nn - j0, PRCH);
        __syncthreads();
        for (int j = tid; j < jn; j += 256)
            kj[j] = rkey(score[j0 + j], j0 + j);
        __syncthreads();
        for (int j = lane; j < jn; j += 64) {
            unsigned long long kv = kj[j];
            #pragma unroll
            for (int r = 0; r < 4; ++r) cnt[r] += (kv > ki[r]) ? 1 : 0;
        }
    }
    #pragma unroll
    for (int r = 0; r < 4; ++r) {
        int c = cnt[r];
        for (int off = 32; off > 0; off >>= 1) c += __shfl_down(c, off, 64);
        cnt[r] = __shfl(c, 0, 64);
    }
    for (int r = 0; r < 4; ++r) {
        int i = i0 + r;
        if (i >= Nn) break;
        int rk = (cnt[r] < kk) ? cnt[r] : -1;
        if (lane == 0) rank_out[i] = rk;
        if (scale_out && lane == 1) scale_out[i] = tanhf(score[i] * invn[0]);
        if (!Xb || rk < 0) continue;
        float sc = tanhf(score[i] * invn[0]);
        const ushort4* src = (const ushort4*)(Hb + (size_t)i * HID);
        ushort4* dst = (ushort4*)(Xb + (size_t)rk * HID);
        ushort4 u = src[lane];
        ushort4 o;
        o.x = bf16rn(bf2f(u.x) * sc); o.y = bf16rn(bf2f(u.y) * sc);
        o.z = bf16rn(bf2f(u.z) * sc); o.w = bf16rn(bf2f(u.w) * sc);
        dst[lane] = o;
        if (lane < HID / 4 - 64) {
            ushort4 u2 = src[lane + 64];
            ushort4 o2;
            o2.x = bf16rn(bf2f(u2.x) * sc); o2.y = bf16rn(bf2f(u2.y) * sc);
            o2.z = bf16rn(bf2f(u2.z) * sc); o2.w = bf16rn(bf2f(u2.w) * sc);
            dst[lane + 64] = o2;
        }
    }
}

// shared readout slab body: per-slab column max+sum over bf16 rows
__device__ void readout_slab(const unsigned short* __restrict__ X, int rows, int rpb,
                             int slabY, int colHalf,
                             float* __restrict__ pmax, float* __restrict__ psum) {
    __shared__ float4 lmx[4][64];
    __shared__ float4 lsm[4][64];
    int lane = threadIdx.x & 63;
    int rgrp = threadIdx.x >> 6;
    int c4 = colHalf * 64 + lane;
    int r0 = slabY * rpb;
    int r1 = min(rows, r0 + rpb);
    float4 mx = make_float4(-INFINITY, -INFINITY, -INFINITY, -INFINITY);
    float4 sm = make_float4(0.f, 0.f, 0.f, 0.f);
    if (c4 < HID / 4) {
        for (int r = r0 + rgrp; r < r1; r += 4) {
            ushort4 u = *(const ushort4*)(X + (size_t)r * HID + c4 * 4);
            float vx = bf2f(u.x), vy = bf2f(u.y), vz = bf2f(u.z), vw = bf2f(u.w);
            mx.x = fmaxf(mx.x, vx); mx.y = fmaxf(mx.y, vy);
            mx.z = fmaxf(mx.z, vz); mx.w = fmaxf(mx.w, vw);
            sm.x += vx; sm.y += vy; sm.z += vz; sm.w += vw;
        }
    }
    lmx[rgrp][lane] = mx; lsm[rgrp][lane] = sm;
    __syncthreads();
    if (rgrp == 0 && c4 < HID / 4) {
        #pragma unroll
        for (int g = 1; g < 4; ++g) {
            float4 m2 = lmx[g][lane], s2 = lsm[g][lane];
            mx.x = fmaxf(mx.x, m2.x); mx.y = fmaxf(mx.y, m2.y);
            mx.z = fmaxf(mx.z, m2.z); mx.w = fmaxf(mx.w, m2.w);
            sm.x += s2.x; sm.y += s2.y; sm.z += s2.z; sm.w += s2.w;
        }
        *(float4*)(pmax + (size_t)slabY * HID + c4 * 4) = mx;
        *(float4*)(psum + (size_t)slabY * HID + c4 * 4) = sm;
    }
}

// role-split: blocks <2500 do conv2 aggregation; the rest do pool1 readout
__global__ __launch_bounds__(256) void k_g2r1(
    const unsigned short* __restrict__ xp1, const int* __restrict__ offs,
    const int2* __restrict__ ce, const int* __restrict__ rank,
    unsigned short* __restrict__ aggb,
    float* __restrict__ pm1, float* __restrict__ ps1) {
    if (blockIdx.x < 2500) {
        int wave = (blockIdx.x * 256 + threadIdx.x) >> 6;
        int lane = threadIdx.x & 63;
        int rd = rank[wave];
        if (rd < 0) return;
        int b = offs[wave], e = offs[wave + 1];
        int c1 = 256 + lane * 4;
        float a0 = 0.f, a1 = 0.f, a2 = 0.f, a3 = 0.f;
        float b0 = 0.f, b1v = 0.f, b2 = 0.f, b3 = 0.f;
        int2 nxt = (b < e) ? ce[b] : make_int2(0, 0);
        for (int p = b; p < e; ++p) {
            int2 cur = nxt;
            if (p + 1 < e) nxt = ce[p + 1];
            int rs = rank[cur.x];
            if (rs < 0) continue;
            float we = __int_as_float(cur.y);
            const unsigned short* row = xp1 + (size_t)rs * HID;
            ushort4 u = *(const ushort4*)(row + lane * 4);
            a0 += bf2f(u.x) * we; a1 += bf2f(u.y) * we;
            a2 += bf2f(u.z) * we; a3 += bf2f(u.w) * we;
            if (c1 < HID) {
                ushort4 u2 = *(const ushort4*)(row + c1);
                b0 += bf2f(u2.x) * we; b1v += bf2f(u2.y) * we;
                b2 += bf2f(u2.z) * we; b3 += bf2f(u2.w) * we;
            }
        }
        unsigned short* o = aggb + (size_t)rd * HID;
        ushort4 o1; o1.x = bf16rn(a0); o1.y = bf16rn(a1); o1.z = bf16rn(a2); o1.w = bf16rn(a3);
        *(ushort4*)(o + lane * 4) = o1;
        if (c1 < HID) {
            ushort4 o2; o2.x = bf16rn(b0); o2.y = bf16rn(b1v); o2.z = bf16rn(b2); o2.w = bf16rn(b3);
            *(ushort4*)(o + c1) = o2;
        }
    } else {
        int b = blockIdx.x - 2500;
        readout_slab(xp1, K1, RORPB, b >> 1, b & 1, pm1, ps1);
    }
}

// readout2 directly from hb with rank mask + scale (xp2 never materialized);
// last block (done-counter) folds both pools' slabs -> z[1000].
__global__ __launch_bounds__(256) void k_readout2(
    const unsigned short* __restrict__ hb, const int* __restrict__ rank2,
    const float* __restrict__ scale2,
    float* __restrict__ pm2, float* __restrict__ ps2,
    const float* __restrict__ pm1, const float* __restrict__ ps1,
    float* __restrict__ z, int* __restrict__ donectr) {
    __shared__ float4 lmx[4][64];
    __shared__ float4 lsm[4][64];
    __shared__ int flag;
    int tid = threadIdx.x;
    int lane = tid & 63;
    int rgrp = tid >> 6;
    int slabY = blockIdx.x >> 1, colHalf = blockIdx.x & 1;
    int c4 = colHalf * 64 + lane;
    int r0 = slabY * RORPB;
    int r1 = min(NN2, r0 + RORPB);
    float4 mx = make_float4(-INFINITY, -INFINITY, -INFINITY, -INFINITY);
    float4 sm = make_float4(0.f, 0.f, 0.f, 0.f);
    if (c4 < HID / 4) {
        for (int r = r0 + rgrp; r < r1; r += 4) {
            if (rank2[r] < 0) continue;
            float sc = scale2[r];
            ushort4 u = *(const ushort4*)(hb + (size_t)r * HID + c4 * 4);
            float vx = bf2f(u.x) * sc, vy = bf2f(u.y) * sc;
            float vz = bf2f(u.z) * sc, vw = bf2f(u.w) * sc;
            mx.x = fmaxf(mx.x, vx); mx.y = fmaxf(mx.y, vy);
            mx.z = fmaxf(mx.z, vz); mx.w = fmaxf(mx.w, vw);
            sm.x += vx; sm.y += vy; sm.z += vz; sm.w += vw;
        }
    }
    lmx[rgrp][lane] = mx; lsm[rgrp][lane] = sm;
    __syncthreads();
    if (rgrp == 0 && c4 < HID / 4) {
        #pragma unroll
        for (int g = 1; g < 4; ++g) {
            float4 m2 = lmx[g][lane], s2 = lsm[g][lane];
            mx.x = fmaxf(mx.x, m2.x); mx.y = fmaxf(mx.y, m2.y);
            mx.z = fmaxf(mx.z, m2.z); mx.w = fmaxf(mx.w, m2.w);
            sm.x += s2.x; sm.y += s2.y; sm.z += s2.z; sm.w += s2.w;
        }
        *(float4*)(pm2 + (size_t)slabY * HID + c4 * 4) = mx;
        *(float4*)(ps2 + (size_t)slabY * HID + c4 * 4) = sm;
    }
    // done-counter: last block combines both pools -> z
    if (tid == 0) {
        __threadfence();
        flag = (atomicAdd(donectr, 1) == (int)gridDim.x - 1) ? 1 : 0;
    }
    __syncthreads();
    if (!flag) return;
    __threadfence();
    for (int j = tid; j < HID; j += 256) {
        float m1 = -INFINITY, s1 = 0.f, m2v = -INFINITY, s2v = 0.f;
        for (int s = 0; s < NSLAB; ++s) {
            m1 = fmaxf(m1, pm1[(size_t)s * HID + j]); s1 += ps1[(size_t)s * HID + j];
            m2v = fmaxf(m2v, pm2[(size_t)s * HID + j]); s2v += ps2[(size_t)s * HID + j];
        }
        z[j] = m1 + m2v;
        z[HID + j] = s1 * (1.0f / (float)K1) + s2v * (1.0f / (float)K2);
    }
}

__global__ __launch_bounds__(256) void k_mv(
    const float* __restrict__ v, const float* __restrict__ W,
    const float* __restrict__ bias, float* __restrict__ y,
    int rowsN, int K, int act) {
    int wave = (blockIdx.x * 256 + threadIdx.x) >> 6;
    int lane = threadIdx.x & 63;
    if (wave >= rowsN) return;
    const float* wr = W + (size_t)wave * K;
    float s = 0.f;
    for (int c = lane * 4; c < K; c += 256) {
        float4 a = *(const float4*)(wr + c);
        float4 xv = *(const float4*)(v + c);
        s += a.x * xv.x + a.y * xv.y + a.z * xv.z + a.w * xv.w;
    }
    for (int off = 32; off > 0; off >>= 1) s += __shfl_down(s, off, 64);
    if (lane == 0) {
        float r = s + bias[wave];
        y[wave] = (act == 0) ? fmaxf(r, 0.f) : 1.f / (1.f + expf(-r));
    }
}

// ---------------- launch ----------------
extern "C" void kernel_launch(void* const* d_in, const int* in_sizes, int n_in,
                              void* d_out, int out_size, void* d_ws, size_t ws_size,
                              hipStream_t stream) {
    const float* x      = (const float*)d_in[0];
    const int*   esrc   = (const int*)d_in[1];
    const int*   edst   = (const int*)d_in[2];
    const float* ew     = (const float*)d_in[3];
    const float* W1_rel = (const float*)d_in[4];
    const float* b1     = (const float*)d_in[5];
    const float* W1_root= (const float*)d_in[6];
    const float* p1     = (const float*)d_in[7];
    const float* W2_rel = (const float*)d_in[8];
    const float* b2     = (const float*)d_in[9];
    const float* W2_root= (const float*)d_in[10];
    const float* p2     = (const float*)d_in[11];
    const float* l1W    = (const float*)d_in[12];
    const float* l1b    = (const float*)d_in[13];
    const float* l2W    = (const float*)d_in[14];
    const float* l2b    = (const float*)d_in[15];
    const float* l3W    = (const float*)d_in[16];
    const float* l3b    = (const float*)d_in[17];
    float* out = (float*)d_out;
    float* ws  = (float*)d_ws;

    if (ws_size < (size_t)WS_FLOATS * sizeof(float)) return;

    int*            offs   = (int*)(ws + CSR_OFFS);
    int*            pos    = (int*)(ws + CSR_POS);
    float*          score1 = ws + OFF_SC1;
    float*          score2 = ws + OFF_SC2;
    int*            ctr    = (int*)(ws + OFF_CTR);
    int2*           ce     = (int2*)(ws + CSR_EDGE);
    float*          scale2 = ws + OFF_SCALE2;
    int*            rk1    = (int*)(ws + OFF_RK1);
    int*            rk2    = (int*)(ws + OFF_RK2);
    float*          pm1    = ws + OFF_PM1;
    float*          ps1    = ws + OFF_PS1;
    float*          pm2    = ws + OFF_PM2;
    float*          ps2    = ws + OFF_PS2;
    float*          zbuf   = ws + OFF_Z;
    float*          t1     = ws + OFF_T1;
    float*          t2     = ws + OFF_T2;
    float*          invn   = ws + OFF_INV;
    unsigned short* aggb   = (unsigned short*)(ws + OFF_AGG);
    unsigned short* hb     = (unsigned short*)(ws + OFF_H);
    unsigned short* xp1b   = (unsigned short*)(ws + OFF_XP1B);
    unsigned short* xb     = (unsigned short*)(ws + OFF_XB);
    unsigned short* w1rb   = (unsigned short*)(ws + OFF_W1RB);
    unsigned short* w1tb   = (unsigned short*)(ws + OFF_W1TB);
    unsigned short* w2rb   = (unsigned short*)(ws + OFF_W2RB);
    unsigned short* w2tb   = (unsigned short*)(ws + OFF_W2TB);

    // zero: pos, score1, score2, counters (one contiguous range)
    hipMemsetAsync(ws + ZERO_BASE, 0, (size_t)ZERO_LEN * sizeof(float), stream);

    k_prep<<<dim3(640, 7), 256, 0, stream>>>(
        x, xb, W1_rel, w1rb, W1_root, w1tb, W2_rel, w2rb, W2_root, w2tb,
        p1, p2, invn, edst, pos);
    k_scan<<<1, 1024, 0, stream>>>(pos, offs);
    k_fill<<<(NE + 255) / 256, 256, 0, stream>>>(esrc, edst, ew, pos, ce);

    // conv1 (+fused score atomics)
    k_gather1<<<(NN1 * 64) / 256, 256, 0, stream>>>(xb, offs, ce, aggb);
    {
        int nby = (NN1 + 63) / 64;                 // 157
        int nblk = 64 * ((nby + 7) / 8);           // 1280
        k_gemm_bf16<<<nblk, 256, 0, stream>>>(
            aggb, w1rb, xb, w1tb, b1, p1, hb, score1, NN1, HID, FIN, FIN, nby);
    }

    // pool1: single-kernel rank + gather (full parallelism: 625 blocks)
    k_poolrank<<<625, 256, 0, stream>>>(
        hb, score1, invn + 0, NN1, K1, rk1, (float*)nullptr, xp1b);

    // conv2 aggregation || pool1 readout, then conv2 GEMM
    k_g2r1<<<2500 + 2 * NSLAB, 256, 0, stream>>>(xp1b, offs, ce, rk1, aggb, pm1, ps1);
    {
        int nby = (NN2 + 63) / 64;                 // 79
        int nblk = 64 * ((nby + 7) / 8);           // 640
        k_gemm_bf16<<<nblk, 256, 0, stream>>>(
            aggb, w2rb, xp1b, w2tb, b2, p2, hb, score2, NN2, HID, HID, HID, nby);
    }

    // pool2: single-kernel rank (+tanh scale), no gather (313 blocks)
    k_poolrank<<<313, 256, 0, stream>>>(
        hb, score2, invn + 1, NN2, K2, rk2, scale2, (unsigned short*)nullptr);

    // readout2 (mask+scale directly from hb) + fused combine -> z
    k_readout2<<<2 * NSLAB, 256, 0, stream>>>(
        hb, rk2, scale2, pm2, ps2, pm1, ps1, zbuf, ctr + 3);

    // MLP
    k_mv<<<(2000 * 64) / 256, 256, 0, stream>>>(zbuf, l1W, l1b, t1, 2000, 1000, 0);
    k_mv<<<(4000 * 64) / 256, 256, 0, stream>>>(t1, l2W, l2b, t2, 4000, 2000, 0);
    k_mv<<<(100 * 64) / 256, 256, 0, stream>>>(t2, l3W, l3b, out, 100, 4000, 1);
}

// Round 10
// 314.535 us; speedup vs baseline: 1.1652x; 1.0287x over previous
//
#include <hip/hip_runtime.h>
#include <math.h>

// ---------------- sizes ----------------
#define NN1   10000
#define NE    160000
#define FIN   256
#define HID   500
#define K1    5000
#define NN2   5000
#define K2    2500
#define NSLAB 64
#define RORPB  79
#define RCHUNK 500

// ---------------- ws layout (float offsets) ----------------
#define CSR_OFFS   0u        // 10008 ints (offs[0..10000])
#define CSR_POS    10008u    // 10000 ints  (zeroed)
#define OFF_SC1    20008u    // 10000 f     (zeroed)
#define OFF_SC2    30008u    // 5000 f      (zeroed)
#define OFF_CTR    35008u    // 32 ints     (zeroed): 3 readout2
#define ZERO_BASE  10008u
#define ZERO_LEN   25032u
#define CSR_EDGE   35040u    // int2 x 160000 -> 320000 floats
#define OFF_SCALE1 355040u   // 10000 (unused, kept for layout stability)
#define OFF_SCALE2 365040u   // 5000
#define OFF_RK1    370040u   // 10000 ints
#define OFF_RK2    380040u   // 5000 ints
#define OFF_PM1    385056u   // 64*500
#define OFF_PS1    417056u
#define OFF_PM2    449056u
#define OFF_PS2    481056u
#define OFF_Z      513056u   // 1000
#define OFF_T1     514056u   // 2000
#define OFF_T2     516056u   // 4000
#define OFF_INV    520056u   // 2 (+pad)
#define OFF_AGG    520064u   // bf16: max(10000*256, 5000*500) -> 1.28M floats
#define OFF_H      1800064u  // bf16 10000*500 -> 2.5M floats
#define OFF_XP1B   4300064u  // bf16 5000*500
#define OFF_XB     6175064u  // bf16 10000*256
#define OFF_W1RB   7455064u
#define OFF_W1TB   7519064u
#define OFF_W2RB   7583064u
#define OFF_W2TB   7708064u
#define OFF_CNT    7833088u  // 200000 ints (rank partial counts)
#define WS_FLOATS  8033120u

// ---------------- helpers ----------------
__device__ inline unsigned f2ord(float f) {
    unsigned u = __float_as_uint(f);
    return (u & 0x80000000u) ? ~u : (u | 0x80000000u);
}
__device__ inline unsigned long long rkey(float s, int j) {
    return ((unsigned long long)f2ord(s) << 32) | (unsigned)(0xFFFFFFFFu - (unsigned)j);
}
__device__ inline unsigned short bf16rn(float f) {
    unsigned u = __float_as_uint(f);
    u += 0x7FFFu + ((u >> 16) & 1u);
    return (unsigned short)(u >> 16);
}
__device__ inline float bf2f(unsigned short u) {
    return __uint_as_float((unsigned)u << 16);
}

typedef __attribute__((ext_vector_type(8))) short short8;
typedef __attribute__((ext_vector_type(4))) float floatx4;

// guarded 16B bf16 load
__device__ inline short8 ld8g(const unsigned short* p, int gk, int K) {
    if (gk + 7 < K) return *(const short8*)p;
    unsigned short tmp[8] = {0,0,0,0,0,0,0,0};
    for (int q = 0; q < 8; ++q) if (gk + q < K) tmp[q] = p[q];
    return *(short8*)tmp;
}

// ---------------- kernels ----------------

// fused prep: y<5 fp32->bf16 convert (grid-stride, 640 blocks/slice — was 2500
// single-shot: 17500 tiny blocks ~= dispatch-rate bound); y==5 p-norms;
// y==6 degree histogram (grid-stride). Scan stays a separate kernel (r4 lesson:
// keep variables separable).
__global__ __launch_bounds__(256) void k_prep(
    const float* __restrict__ x, unsigned short* __restrict__ xb,
    const float* __restrict__ w1r, unsigned short* __restrict__ w1rb,
    const float* __restrict__ w1t, unsigned short* __restrict__ w1tb,
    const float* __restrict__ w2r, unsigned short* __restrict__ w2rb,
    const float* __restrict__ w2t, unsigned short* __restrict__ w2tb,
    const float* __restrict__ p1, const float* __restrict__ p2,
    float* __restrict__ invn,
    const int* __restrict__ edst, int* __restrict__ pos) {
    __shared__ float red[256];
    int tid = threadIdx.x;
    int y = blockIdx.y;
    if (y < 5) {
        const float* s; unsigned short* d; int n4;
        switch (y) {
            case 0: s = x;   d = xb;   n4 = NN1 * FIN / 4; break;
            case 1: s = w1r; d = w1rb; n4 = HID * FIN / 4; break;
            case 2: s = w1t; d = w1tb; n4 = HID * FIN / 4; break;
            case 3: s = w2r; d = w2rb; n4 = HID * HID / 4; break;
            default: s = w2t; d = w2tb; n4 = HID * HID / 4; break;
        }
        int stride = gridDim.x * 256;
        for (int i = blockIdx.x * 256 + tid; i < n4; i += stride) {
            float4 v = *(const float4*)(s + (size_t)i * 4);
            ushort4 o;
            o.x = bf16rn(v.x); o.y = bf16rn(v.y); o.z = bf16rn(v.z); o.w = bf16rn(v.w);
            *(ushort4*)(d + (size_t)i * 4) = o;
        }
    } else if (y == 5) {
        if (blockIdx.x >= 2) return;
        const float* p = blockIdx.x ? p2 : p1;
        float s = 0.f;
        for (int i = tid; i < HID; i += 256) { float v = p[i]; s += v * v; }
        red[tid] = s; __syncthreads();
        for (int w = 128; w > 0; w >>= 1) {
            if (tid < w) red[tid] += red[tid + w];
            __syncthreads();
        }
        if (tid == 0) invn[blockIdx.x] = 1.0f / sqrtf(red[0]);
    } else {
        int stride = gridDim.x * 256;
        for (int e = blockIdx.x * 256 + tid; e < NE; e += stride)
            atomicAdd(&pos[edst[e]], 1);
    }
}

// single-block exclusive scan; writes offs[0..NN1] AND pos working copy
__global__ __launch_bounds__(1024) void k_scan(int* __restrict__ pos, int* __restrict__ offs) {
    __shared__ int tot[1024];
    int t = threadIdx.x;
    int base = t * 10;
    int loc[10]; int s = 0;
    #pragma unroll
    for (int q = 0; q < 10; ++q) {
        int v = (base + q < NN1) ? pos[base + q] : 0;
        loc[q] = s; s += v;
    }
    tot[t] = s; __syncthreads();
    for (int d = 1; d < 1024; d <<= 1) {
        int v = (t >= d) ? tot[t - d] : 0;
        __syncthreads();
        tot[t] += v;
        __syncthreads();
    }
    int excl = (t == 0) ? 0 : tot[t - 1];
    #pragma unroll
    for (int q = 0; q < 10; ++q)
        if (base + q < NN1) { int o = excl + loc[q]; offs[base + q] = o; pos[base + q] = o; }
    if (t == 1023) offs[NN1] = tot[1023];
}

// fill packed edges: one 8B store per edge
__global__ __launch_bounds__(256) void k_fill(
    const int* __restrict__ src, const int* __restrict__ dst,
    const float* __restrict__ w, int* __restrict__ pos,
    int2* __restrict__ ce) {
    int e = blockIdx.x * 256 + threadIdx.x;
    if (e >= NE) return;
    int slot = atomicAdd(&pos[dst[e]], 1);
    ce[slot] = make_int2(src[e], __float_as_int(w[e]));
}

// conv1 aggregation, 2-edge unroll with dual accumulator chains
__global__ __launch_bounds__(256) void k_gather1(
    const unsigned short* __restrict__ xb, const int* __restrict__ offs,
    const int2* __restrict__ ce, unsigned short* __restrict__ aggb) {
    int wave = (blockIdx.x * 256 + threadIdx.x) >> 6;
    int lane = threadIdx.x & 63;
    if (wave >= NN1) return;
    int b = offs[wave], e = offs[wave + 1];
    float4 a0 = make_float4(0.f, 0.f, 0.f, 0.f);
    float4 a1 = make_float4(0.f, 0.f, 0.f, 0.f);
    int p = b;
    for (; p + 1 < e; p += 2) {
        int2 e0 = ce[p], e1 = ce[p + 1];
        float w0 = __int_as_float(e0.y), w1 = __int_as_float(e1.y);
        ushort4 u0 = *(const ushort4*)(xb + (size_t)e0.x * FIN + lane * 4);
        ushort4 u1 = *(const ushort4*)(xb + (size_t)e1.x * FIN + lane * 4);
        a0.x += bf2f(u0.x) * w0; a0.y += bf2f(u0.y) * w0;
        a0.z += bf2f(u0.z) * w0; a0.w += bf2f(u0.w) * w0;
        a1.x += bf2f(u1.x) * w1; a1.y += bf2f(u1.y) * w1;
        a1.z += bf2f(u1.z) * w1; a1.w += bf2f(u1.w) * w1;
    }
    if (p < e) {
        int2 e0 = ce[p];
        float w0 = __int_as_float(e0.y);
        ushort4 u0 = *(const ushort4*)(xb + (size_t)e0.x * FIN + lane * 4);
        a0.x += bf2f(u0.x) * w0; a0.y += bf2f(u0.y) * w0;
        a0.z += bf2f(u0.z) * w0; a0.w += bf2f(u0.w) * w0;
    }
    ushort4 o;
    o.x = bf16rn(a0.x + a1.x); o.y = bf16rn(a0.y + a1.y);
    o.z = bf16rn(a0.z + a1.z); o.w = bf16rn(a0.w + a1.w);
    *(ushort4*)(aggb + (size_t)wave * FIN + lane * 4) = o;
}

// ---- bf16 MFMA GEMM: XOR-swizzled LDS, double-buffered, 2-deep prefetch ----
// C(bf16) = relu(A1@B1^T + A2@B2^T + bias); score[row] += sum(relu*pv) via atomics.
#define GBK 64
__global__ __launch_bounds__(256) void k_gemm_bf16(
    const unsigned short* __restrict__ A1, const unsigned short* __restrict__ B1,
    const unsigned short* __restrict__ A2, const unsigned short* __restrict__ B2,
    const float* __restrict__ bias, const float* __restrict__ pv,
    unsigned short* __restrict__ C, float* __restrict__ score,
    int M, int N, int Ka, int Kb, int nbyRow) {
    __shared__ unsigned short As[2][64 * 64];
    __shared__ unsigned short Bs[2][64 * 64];
    int tid = threadIdx.x;
    int b = blockIdx.x;
    int xcd = b & 7, seq = b >> 3;
    int colT = seq & 7;
    int rowT = xcd + 8 * (seq >> 3);
    if (rowT >= nbyRow) return;
    int row0 = rowT * 64, col0 = colT * 64;
    int lane = tid & 63, wid = tid >> 6;
    int waveM = wid & 1, waveN = wid >> 1;
    int quad = lane >> 4, mrow = lane & 15;
    int m7 = mrow & 7;
    floatx4 acc[2][2] = {};

    int sr = tid >> 2;
    int ca = (tid & 3) * 2;
    int s7 = sr & 7;
    int c0 = (ca ^ s7) * 8;
    int c1 = ((ca + 1) ^ s7) * 8;
    int sbase = sr * 64;

    int nka = (Ka + GBK - 1) / GBK;
    int nkb = (Kb + GBK - 1) / GBK;
    int niter = nka + nkb;

    short8 z8 = {0,0,0,0,0,0,0,0};
    short8 paA = z8, paB = z8, pbA = z8, pbB = z8;

    auto fetch = [&](int t) {
        int ph = (t >= nka);
        const unsigned short* A = ph ? A2 : A1;
        const unsigned short* B = ph ? B2 : B1;
        int K = ph ? Kb : Ka;
        int gk = (ph ? t - nka : t) * GBK + ca * 8;
        int gr = row0 + sr, gn = col0 + sr;
        paA = z8; paB = z8; pbA = z8; pbB = z8;
        if (gr < M) {
            const unsigned short* p = A + (size_t)gr * K + gk;
            paA = ld8g(p, gk, K); paB = ld8g(p + 8, gk + 8, K);
        }
        if (gn < N) {
            const unsigned short* p = B + (size_t)gn * K + gk;
            pbA = ld8g(p, gk, K); pbB = ld8g(p + 8, gk + 8, K);
        }
    };
    auto commit = [&](int buf) {
        *(short8*)&As[buf][sbase + c0] = paA;
        *(short8*)&As[buf][sbase + c1] = paB;
        *(short8*)&Bs[buf][sbase + c0] = pbA;
        *(short8*)&Bs[buf][sbase + c1] = pbB;
    };

    fetch(0);
    commit(0);
    if (niter > 1) fetch(1);
    __syncthreads();

    for (int it = 0; it < niter; ++it) {
        int cur = it & 1;
        if (it + 1 < niter) commit(cur ^ 1);
        if (it + 2 < niter) fetch(it + 2);
        #pragma unroll
        for (int half = 0; half < 2; ++half) {
            int qc = half * 4 + quad;
            int qoff = (qc ^ m7) * 8;
            short8 bfr[2];
            #pragma unroll
            for (int nt = 0; nt < 2; ++nt)
                bfr[nt] = *(short8*)&Bs[cur][(waveN * 32 + nt * 16 + mrow) * 64 + qoff];
            #pragma unroll
            for (int mt = 0; mt < 2; ++mt) {
                short8 afr = *(short8*)&As[cur][(waveM * 32 + mt * 16 + mrow) * 64 + qoff];
                #pragma unroll
                for (int nt = 0; nt < 2; ++nt)
                    acc[mt][nt] = __builtin_amdgcn_mfma_f32_16x16x32_bf16(
                        afr, bfr[nt], acc[mt][nt], 0, 0, 0);
            }
        }
        __syncthreads();
    }
    // epilogue: bias + relu -> bf16 C; score partials via atomics
    float ps[2][4] = {};
    #pragma unroll
    for (int nt = 0; nt < 2; ++nt) {
        int col = col0 + waveN * 32 + nt * 16 + mrow;
        if (col >= N) continue;
        float bv = bias[col];
        float pc = pv[col];
        #pragma unroll
        for (int mt = 0; mt < 2; ++mt) {
            int rbase = row0 + waveM * 32 + mt * 16 + quad * 4;
            #pragma unroll
            for (int r = 0; r < 4; ++r) {
                float v = fmaxf(acc[mt][nt][r] + bv, 0.f);
                int row = rbase + r;
                if (row < M) C[(size_t)row * N + col] = bf16rn(v);
                ps[mt][r] += v * pc;
            }
        }
    }
    #pragma unroll
    for (int mt = 0; mt < 2; ++mt)
        #pragma unroll
        for (int r = 0; r < 4; ++r) {
            float v = ps[mt][r];
            v += __shfl_xor(v, 1, 64); v += __shfl_xor(v, 2, 64);
            v += __shfl_xor(v, 4, 64); v += __shfl_xor(v, 8, 64);
            if (mrow == 0) {
                int row = row0 + waveM * 32 + mt * 16 + quad * 4 + r;
                if (row < M) atomicAdd(&score[row], v);
            }
        }
}

// parallel count-based rank partials: cntp[chunkY][i] = |{j in chunk : key_j > key_i}|
__global__ __launch_bounds__(256) void k_rank_partial(
    const float* __restrict__ score, int* __restrict__ cntp, int Nn) {
    __shared__ unsigned long long kj[RCHUNK];
    int j0 = blockIdx.y * RCHUNK;
    int jn = min(Nn - j0, RCHUNK);
    for (int t = threadIdx.x; t < jn; t += 256)
        kj[t] = rkey(score[j0 + t], j0 + t);
    __syncthreads();
    int i = blockIdx.x * 256 + threadIdx.x;
    if (i >= Nn) return;
    unsigned long long ki = rkey(score[i], i);
    int c = 0;
    #pragma unroll 4
    for (int q = 0; q < jn; ++q)
        c += (kj[q] > ki) ? 1 : 0;
    cntp[(size_t)blockIdx.y * Nn + i] = c;
}

// pool1: wave-per-row rank finalize + gather (was 10000 x 128-thread blocks:
// dispatch-rate bound + half-idle blocks). 1250 blocks, each wave does 2 rows.
__global__ __launch_bounds__(256) void k_gather_pool(
    const unsigned short* __restrict__ Hb, const float* __restrict__ score,
    const float* __restrict__ invn,
    const int* __restrict__ cntp, int Nn, int nchunk, int kk,
    int* __restrict__ rank_out, unsigned short* __restrict__ Xb) {
    int wave = (blockIdx.x * 256 + threadIdx.x) >> 6;
    int lane = threadIdx.x & 63;
    int nw = gridDim.x * 4;
    for (int i = wave; i < Nn; i += nw) {
        int c = (lane < nchunk) ? cntp[(size_t)lane * Nn + i] : 0;
        for (int off = 32; off > 0; off >>= 1) c += __shfl_down(c, off, 64);
        c = __shfl(c, 0, 64);
        int r = (c < kk) ? c : -1;
        if (lane == 0) rank_out[i] = r;
        if (r < 0) continue;
        float sc = tanhf(score[i] * invn[0]);
        const ushort4* src = (const ushort4*)(Hb + (size_t)i * HID);
        ushort4* dst = (ushort4*)(Xb + (size_t)r * HID);
        ushort4 u = src[lane];
        ushort4 o;
        o.x = bf16rn(bf2f(u.x) * sc); o.y = bf16rn(bf2f(u.y) * sc);
        o.z = bf16rn(bf2f(u.z) * sc); o.w = bf16rn(bf2f(u.w) * sc);
        dst[lane] = o;
        if (lane < HID / 4 - 64) {
            ushort4 u2 = src[lane + 64];
            ushort4 o2;
            o2.x = bf16rn(bf2f(u2.x) * sc); o2.y = bf16rn(bf2f(u2.y) * sc);
            o2.z = bf16rn(bf2f(u2.z) * sc); o2.w = bf16rn(bf2f(u2.w) * sc);
            dst[lane + 64] = o2;
        }
    }
}

// pool2: rank + scale only (no row gather; readout2 reads hb directly)
__global__ __launch_bounds__(256) void k_rank_fin2(
    const float* __restrict__ score, const float* __restrict__ invn,
    const int* __restrict__ cntp, int Nn, int nchunk, int kk,
    int* __restrict__ rank_out, float* __restrict__ scale_out) {
    int i = blockIdx.x * 256 + threadIdx.x;
    if (i >= Nn) return;
    int t = 0;
    for (int q = 0; q < nchunk; ++q) t += cntp[(size_t)q * Nn + i];
    rank_out[i] = (t < kk) ? t : -1;
    scale_out[i] = tanhf(score[i] * invn[0]);
}

// shared readout slab body: per-slab column max+sum over bf16 rows
__device__ void readout_slab(const unsigned short* __restrict__ X, int rows, int rpb,
                             int slabY, int colHalf,
                             float* __restrict__ pmax, float* __restrict__ psum) {
    __shared__ float4 lmx[4][64];
    __shared__ float4 lsm[4][64];
    int lane = threadIdx.x & 63;
    int rgrp = threadIdx.x >> 6;
    int c4 = colHalf * 64 + lane;
    int r0 = slabY * rpb;
    int r1 = min(rows, r0 + rpb);
    float4 mx = make_float4(-INFINITY, -INFINITY, -INFINITY, -INFINITY);
    float4 sm = make_float4(0.f, 0.f, 0.f, 0.f);
    if (c4 < HID / 4) {
        for (int r = r0 + rgrp; r < r1; r += 4) {
            ushort4 u = *(const ushort4*)(X + (size_t)r * HID + c4 * 4);
            float vx = bf2f(u.x), vy = bf2f(u.y), vz = bf2f(u.z), vw = bf2f(u.w);
            mx.x = fmaxf(mx.x, vx); mx.y = fmaxf(mx.y, vy);
            mx.z = fmaxf(mx.z, vz); mx.w = fmaxf(mx.w, vw);
            sm.x += vx; sm.y += vy; sm.z += vz; sm.w += vw;
        }
    }
    lmx[rgrp][lane] = mx; lsm[rgrp][lane] = sm;
    __syncthreads();
    if (rgrp == 0 && c4 < HID / 4) {
        #pragma unroll
        for (int g = 1; g < 4; ++g) {
            float4 m2 = lmx[g][lane], s2 = lsm[g][lane];
            mx.x = fmaxf(mx.x, m2.x); mx.y = fmaxf(mx.y, m2.y);
            mx.z = fmaxf(mx.z, m2.z); mx.w = fmaxf(mx.w, m2.w);
            sm.x += s2.x; sm.y += s2.y; sm.z += s2.z; sm.w += s2.w;
        }
        *(float4*)(pmax + (size_t)slabY * HID + c4 * 4) = mx;
        *(float4*)(psum + (size_t)slabY * HID + c4 * 4) = sm;
    }
}

// role-split: blocks <2500 do conv2 aggregation; the rest do pool1 readout
__global__ __launch_bounds__(256) void k_g2r1(
    const unsigned short* __restrict__ xp1, const int* __restrict__ offs,
    const int2* __restrict__ ce, const int* __restrict__ rank,
    unsigned short* __restrict__ aggb,
    float* __restrict__ pm1, float* __restrict__ ps1) {
    if (blockIdx.x < 2500) {
        int wave = (blockIdx.x * 256 + threadIdx.x) >> 6;
        int lane = threadIdx.x & 63;
        int rd = rank[wave];
        if (rd < 0) return;
        int b = offs[wave], e = offs[wave + 1];
        int c1 = 256 + lane * 4;
        float a0 = 0.f, a1 = 0.f, a2 = 0.f, a3 = 0.f;
        float b0 = 0.f, b1v = 0.f, b2 = 0.f, b3 = 0.f;
        int2 nxt = (b < e) ? ce[b] : make_int2(0, 0);
        for (int p = b; p < e; ++p) {
            int2 cur = nxt;
            if (p + 1 < e) nxt = ce[p + 1];
            int rs = rank[cur.x];
            if (rs < 0) continue;
            float we = __int_as_float(cur.y);
            const unsigned short* row = xp1 + (size_t)rs * HID;
            ushort4 u = *(const ushort4*)(row + lane * 4);
            a0 += bf2f(u.x) * we; a1 += bf2f(u.y) * we;
            a2 += bf2f(u.z) * we; a3 += bf2f(u.w) * we;
            if (c1 < HID) {
                ushort4 u2 = *(const ushort4*)(row + c1);
                b0 += bf2f(u2.x) * we; b1v += bf2f(u2.y) * we;
                b2 += bf2f(u2.z) * we; b3 += bf2f(u2.w) * we;
            }
        }
        unsigned short* o = aggb + (size_t)rd * HID;
        ushort4 o1; o1.x = bf16rn(a0); o1.y = bf16rn(a1); o1.z = bf16rn(a2); o1.w = bf16rn(a3);
        *(ushort4*)(o + lane * 4) = o1;
        if (c1 < HID) {
            ushort4 o2; o2.x = bf16rn(b0); o2.y = bf16rn(b1v); o2.z = bf16rn(b2); o2.w = bf16rn(b3);
            *(ushort4*)(o + c1) = o2;
        }
    } else {
        int b = blockIdx.x - 2500;
        readout_slab(xp1, K1, RORPB, b >> 1, b & 1, pm1, ps1);
    }
}

// readout2 directly from hb with rank mask + scale (xp2 never materialized);
// last block (done-counter) folds both pools' slabs -> z[1000].
__global__ __launch_bounds__(256) void k_readout2(
    const unsigned short* __restrict__ hb, const int* __restrict__ rank2,
    const float* __restrict__ scale2,
    float* __restrict__ pm2, float* __restrict__ ps2,
    const float* __restrict__ pm1, const float* __restrict__ ps1,
    float* __restrict__ z, int* __restrict__ donectr) {
    __shared__ float4 lmx[4][64];
    __shared__ float4 lsm[4][64];
    __shared__ int flag;
    int tid = threadIdx.x;
    int lane = tid & 63;
    int rgrp = tid >> 6;
    int slabY = blockIdx.x >> 1, colHalf = blockIdx.x & 1;
    int c4 = colHalf * 64 + lane;
    int r0 = slabY * RORPB;
    int r1 = min(NN2, r0 + RORPB);
    float4 mx = make_float4(-INFINITY, -INFINITY, -INFINITY, -INFINITY);
    float4 sm = make_float4(0.f, 0.f, 0.f, 0.f);
    if (c4 < HID / 4) {
        for (int r = r0 + rgrp; r < r1; r += 4) {
            if (rank2[r] < 0) continue;
            float sc = scale2[r];
            ushort4 u = *(const ushort4*)(hb + (size_t)r * HID + c4 * 4);
            float vx = bf2f(u.x) * sc, vy = bf2f(u.y) * sc;
            float vz = bf2f(u.z) * sc, vw = bf2f(u.w) * sc;
            mx.x = fmaxf(mx.x, vx); mx.y = fmaxf(mx.y, vy);
            mx.z = fmaxf(mx.z, vz); mx.w = fmaxf(mx.w, vw);
            sm.x += vx; sm.y += vy; sm.z += vz; sm.w += vw;
        }
    }
    lmx[rgrp][lane] = mx; lsm[rgrp][lane] = sm;
    __syncthreads();
    if (rgrp == 0 && c4 < HID / 4) {
        #pragma unroll
        for (int g = 1; g < 4; ++g) {
            float4 m2 = lmx[g][lane], s2 = lsm[g][lane];
            mx.x = fmaxf(mx.x, m2.x); mx.y = fmaxf(mx.y, m2.y);
            mx.z = fmaxf(mx.z, m2.z); mx.w = fmaxf(mx.w, m2.w);
            sm.x += s2.x; sm.y += s2.y; sm.z += s2.z; sm.w += s2.w;
        }
        *(float4*)(pm2 + (size_t)slabY * HID + c4 * 4) = mx;
        *(float4*)(ps2 + (size_t)slabY * HID + c4 * 4) = sm;
    }
    // done-counter: last block combines both pools -> z
    if (tid == 0) {
        __threadfence();
        flag = (atomicAdd(donectr, 1) == (int)gridDim.x - 1) ? 1 : 0;
    }
    __syncthreads();
    if (!flag) return;
    __threadfence();
    for (int j = tid; j < HID; j += 256) {
        float m1 = -INFINITY, s1 = 0.f, m2v = -INFINITY, s2v = 0.f;
        for (int s = 0; s < NSLAB; ++s) {
            m1 = fmaxf(m1, pm1[(size_t)s * HID + j]); s1 += ps1[(size_t)s * HID + j];
            m2v = fmaxf(m2v, pm2[(size_t)s * HID + j]); s2v += ps2[(size_t)s * HID + j];
        }
        z[j] = m1 + m2v;
        z[HID + j] = s1 * (1.0f / (float)K1) + s2v * (1.0f / (float)K2);
    }
}

__global__ __launch_bounds__(256) void k_mv(
    const float* __restrict__ v, const float* __restrict__ W,
    const float* __restrict__ bias, float* __restrict__ y,
    int rowsN, int K, int act) {
    int wave = (blockIdx.x * 256 + threadIdx.x) >> 6;
    int lane = threadIdx.x & 63;
    if (wave >= rowsN) return;
    const float* wr = W + (size_t)wave * K;
    float s = 0.f;
    for (int c = lane * 4; c < K; c += 256) {
        float4 a = *(const float4*)(wr + c);
        float4 xv = *(const float4*)(v + c);
        s += a.x * xv.x + a.y * xv.y + a.z * xv.z + a.w * xv.w;
    }
    for (int off = 32; off > 0; off >>= 1) s += __shfl_down(s, off, 64);
    if (lane == 0) {
        float r = s + bias[wave];
        y[wave] = (act == 0) ? fmaxf(r, 0.f) : 1.f / (1.f + expf(-r));
    }
}

// ---------------- launch ----------------
extern "C" void kernel_launch(void* const* d_in, const int* in_sizes, int n_in,
                              void* d_out, int out_size, void* d_ws, size_t ws_size,
                              hipStream_t stream) {
    const float* x      = (const float*)d_in[0];
    const int*   esrc   = (const int*)d_in[1];
    const int*   edst   = (const int*)d_in[2];
    const float* ew     = (const float*)d_in[3];
    const float* W1_rel = (const float*)d_in[4];
    const float* b1     = (const float*)d_in[5];
    const float* W1_root= (const float*)d_in[6];
    const float* p1     = (const float*)d_in[7];
    const float* W2_rel = (const float*)d_in[8];
    const float* b2     = (const float*)d_in[9];
    const float* W2_root= (const float*)d_in[10];
    const float* p2     = (const float*)d_in[11];
    const float* l1W    = (const float*)d_in[12];
    const float* l1b    = (const float*)d_in[13];
    const float* l2W    = (const float*)d_in[14];
    const float* l2b    = (const float*)d_in[15];
    const float* l3W    = (const float*)d_in[16];
    const float* l3b    = (const float*)d_in[17];
    float* out = (float*)d_out;
    float* ws  = (float*)d_ws;

    if (ws_size < (size_t)WS_FLOATS * sizeof(float)) return;

    int*            offs   = (int*)(ws + CSR_OFFS);
    int*            pos    = (int*)(ws + CSR_POS);
    float*          score1 = ws + OFF_SC1;
    float*          score2 = ws + OFF_SC2;
    int*            ctr    = (int*)(ws + OFF_CTR);
    int2*           ce     = (int2*)(ws + CSR_EDGE);
    float*          scale2 = ws + OFF_SCALE2;
    int*            rk1    = (int*)(ws + OFF_RK1);
    int*            rk2    = (int*)(ws + OFF_RK2);
    float*          pm1    = ws + OFF_PM1;
    float*          ps1    = ws + OFF_PS1;
    float*          pm2    = ws + OFF_PM2;
    float*          ps2    = ws + OFF_PS2;
    float*          zbuf   = ws + OFF_Z;
    float*          t1     = ws + OFF_T1;
    float*          t2     = ws + OFF_T2;
    float*          invn   = ws + OFF_INV;
    int*            cntp   = (int*)(ws + OFF_CNT);
    unsigned short* aggb   = (unsigned short*)(ws + OFF_AGG);
    unsigned short* hb     = (unsigned short*)(ws + OFF_H);
    unsigned short* xp1b   = (unsigned short*)(ws + OFF_XP1B);
    unsigned short* xb     = (unsigned short*)(ws + OFF_XB);
    unsigned short* w1rb   = (unsigned short*)(ws + OFF_W1RB);
    unsigned short* w1tb   = (unsigned short*)(ws + OFF_W1TB);
    unsigned short* w2rb   = (unsigned short*)(ws + OFF_W2RB);
    unsigned short* w2tb   = (unsigned short*)(ws + OFF_W2TB);

    // zero: pos, score1, score2, counters (one contiguous range)
    hipMemsetAsync(ws + ZERO_BASE, 0, (size_t)ZERO_LEN * sizeof(float), stream);

    k_prep<<<dim3(640, 7), 256, 0, stream>>>(
        x, xb, W1_rel, w1rb, W1_root, w1tb, W2_rel, w2rb, W2_root, w2tb,
        p1, p2, invn, edst, pos);
    k_scan<<<1, 1024, 0, stream>>>(pos, offs);
    k_fill<<<(NE + 255) / 256, 256, 0, stream>>>(esrc, edst, ew, pos, ce);

    // conv1 (+fused score atomics)
    k_gather1<<<(NN1 * 64) / 256, 256, 0, stream>>>(xb, offs, ce, aggb);
    {
        int nby = (NN1 + 63) / 64;                 // 157
        int nblk = 64 * ((nby + 7) / 8);           // 1280
        k_gemm_bf16<<<nblk, 256, 0, stream>>>(
            aggb, w1rb, xb, w1tb, b1, p1, hb, score1, NN1, HID, FIN, FIN, nby);
    }

    // pool1: parallel count-rank + wave-per-row gather
    k_rank_partial<<<dim3((NN1 + 255) / 256, NN1 / RCHUNK), 256, 0, stream>>>(
        score1, cntp, NN1);
    k_gather_pool<<<1250, 256, 0, stream>>>(
        hb, score1, invn + 0, cntp, NN1, NN1 / RCHUNK, K1, rk1, xp1b);

    // conv2 aggregation || pool1 readout, then conv2 GEMM
    k_g2r1<<<2500 + 2 * NSLAB, 256, 0, stream>>>(xp1b, offs, ce, rk1, aggb, pm1, ps1);
    {
        int nby = (NN2 + 63) / 64;                 // 79
        int nblk = 64 * ((nby + 7) / 8);           // 640
        k_gemm_bf16<<<nblk, 256, 0, stream>>>(
            aggb, w2rb, xp1b, w2tb, b2, p2, hb, score2, NN2, HID, HID, HID, nby);
    }

    // pool2: parallel count-rank (+tanh scale), no row gather
    k_rank_partial<<<dim3((NN2 + 255) / 256, NN2 / RCHUNK), 256, 0, stream>>>(
        score2, cntp, NN2);
    k_rank_fin2<<<(NN2 + 255) / 256, 256, 0, stream>>>(
        score2, invn + 1, cntp, NN2, NN2 / RCHUNK, K2, rk2, scale2);

    // readout2 (mask+scale directly from hb) + fused combine -> z
    k_readout2<<<2 * NSLAB, 256, 0, stream>>>(
        hb, rk2, scale2, pm2, ps2, pm1, ps1, zbuf, ctr + 3);

    // MLP
    k_mv<<<(2000 * 64) / 256, 256, 0, stream>>>(zbuf, l1W, l1b, t1, 2000, 1000, 0);
    k_mv<<<(4000 * 64) / 256, 256, 0, stream>>>(t1, l2W, l2b, t2, 4000, 2000, 0);
    k_mv<<<(100 * 64) / 256, 256, 0, stream>>>(t2, l3W, l3b, out, 100, 4000, 1);
}